// Round 4
// baseline (123.177 us; speedup 1.0000x reference)
//
#include <hip/hip_runtime.h>
#include <stdint.h>

// B=4, S=2048, D=512, H=8, DH=64
#define QSCALE (0.125f * 1.44269504088896340736f)  // 1/sqrt(DH) * log2(e), folded into Q
#define MASKNEG (-1.442695e9f)                      // -1e9 * log2(e)

typedef unsigned short u16;
typedef unsigned int u32;
typedef __bf16 bf16x8 __attribute__((ext_vector_type(8)));
typedef __bf16 bf16x4 __attribute__((ext_vector_type(4)));
typedef float f32x4 __attribute__((ext_vector_type(4)));
typedef u16 u16x8 __attribute__((ext_vector_type(8)));

__device__ __forceinline__ u16 f2bf(float f) {
  u32 u = __float_as_uint(f);
  u += 0x7fffu + ((u >> 16) & 1u);  // RNE
  return (u16)(u >> 16);
}

__device__ __forceinline__ void gload16(const void* src, void* ldsbase) {
  __builtin_amdgcn_global_load_lds(
      (const __attribute__((address_space(1))) u32*)src,
      (__attribute__((address_space(3))) u32*)ldsbase, 16, 0, 0);
}

// ---------------- input convert: f32 [B,S,D] -> bf16 [8192][512] ----------------
__global__ __launch_bounds__(256) void conv_in(const float* __restrict__ q,
                                               const float* __restrict__ k,
                                               const float* __restrict__ v,
                                               u16* __restrict__ dst) {
  const float* src = (blockIdx.z == 0) ? q : (blockIdx.z == 1) ? k : v;
  u16* d = dst + (size_t)blockIdx.z * 4194304;
  size_t i = ((size_t)blockIdx.x * 256 + threadIdx.x) * 8;
  float4 a = *(const float4*)(src + i);
  float4 b = *(const float4*)(src + i + 4);
  u16x8 ov;
  ov[0] = f2bf(a.x); ov[1] = f2bf(a.y); ov[2] = f2bf(a.z); ov[3] = f2bf(a.w);
  ov[4] = f2bf(b.x); ov[5] = f2bf(b.y); ov[6] = f2bf(b.z); ov[7] = f2bf(b.w);
  *(u16x8*)(d + i) = ov;
}

// ------------- weight convert+transpose: f32 W[k][n] -> bf16 Wt[n][k] -------------
__global__ __launch_bounds__(256) void conv_w(const float* __restrict__ wq,
                                              const float* __restrict__ wk,
                                              const float* __restrict__ wv,
                                              const float* __restrict__ wo,
                                              u16* __restrict__ wT) {
  const float* src = (blockIdx.z == 0) ? wq : (blockIdx.z == 1) ? wk
                    : (blockIdx.z == 2) ? wv : wo;
  u16* dst = wT + (size_t)blockIdx.z * 262144;
  __shared__ float t[64][65];
  const int n0 = blockIdx.x * 64, k0 = blockIdx.y * 64;
  const int lr = threadIdx.x >> 6, lc = threadIdx.x & 63;
#pragma unroll
  for (int it = 0; it < 16; ++it) {
    const int row = it * 4 + lr;  // k offset
    t[row][lc] = src[(size_t)(k0 + row) * 512 + n0 + lc];
  }
  __syncthreads();
#pragma unroll
  for (int it = 0; it < 16; ++it) {
    const int row = it * 4 + lr;  // n offset
    dst[(size_t)(n0 + row) * 512 + k0 + lc] = f2bf(t[lc][row]);
  }
}

// ---------------- shared GEMM core: C[128,128] += A[128,512] * Bt[128,512]^T ----------------
__device__ __forceinline__ void gemm_core(const u16* __restrict__ A,
                                          const u16* __restrict__ Bt,
                                          int m0, int n0, char* lds,
                                          f32x4 acc[4][4]) {
  const int tid = threadIdx.x;
  const int lane = tid & 63;
  const int wave = tid >> 6;
  const int wm = wave >> 1, wn = wave & 1;
  const int srow = tid >> 3;  // 0..31
  const int sc16 = tid & 7;

  auto stage = [&](int buf, int kt) {
    const int k0 = kt * 64;
    char* base = lds + buf * 32768;
#pragma unroll
    for (int c = 0; c < 4; ++c) {
      const int row = c * 32 + srow;
      const int xc = (sc16 ^ (row & 7)) << 3;
      gload16(A + (size_t)(m0 + row) * 512 + k0 + xc,
              base + c * 4096 + (wave << 10));
      gload16(Bt + (size_t)(n0 + row) * 512 + k0 + xc,
              base + 16384 + c * 4096 + (wave << 10));
    }
  };

  auto compute = [&](int buf) {
    const char* bA = lds + buf * 32768;
    const char* bB = bA + 16384;
#pragma unroll
    for (int kk = 0; kk < 2; ++kk) {
      const int c16 = kk * 4 + (lane >> 4);
      bf16x8 av[4], bv[4];
#pragma unroll
      for (int i = 0; i < 4; ++i) {
        const int row = wm * 64 + i * 16 + (lane & 15);
        av[i] = *(const bf16x8*)(bA + row * 128 + ((c16 ^ (row & 7)) << 4));
      }
#pragma unroll
      for (int j = 0; j < 4; ++j) {
        const int row = wn * 64 + j * 16 + (lane & 15);
        bv[j] = *(const bf16x8*)(bB + row * 128 + ((c16 ^ (row & 7)) << 4));
      }
#pragma unroll
      for (int i = 0; i < 4; ++i)
#pragma unroll
        for (int j = 0; j < 4; ++j)
          acc[i][j] = __builtin_amdgcn_mfma_f32_16x16x32_bf16(av[i], bv[j],
                                                              acc[i][j], 0, 0, 0);
    }
  };

  stage(0, 0);
  __syncthreads();
#pragma unroll
  for (int kt = 0; kt < 8; ++kt) {
    const int cur = kt & 1;
    if (kt < 7) stage(cur ^ 1, kt + 1);
    compute(cur);
    __syncthreads();
  }
}

// ---------------- QKV projection (grid.z selects q/k/v) ----------------
__global__ __launch_bounds__(256) void gemm_qkv(
    const u16* __restrict__ xq, const u16* __restrict__ xk,
    const u16* __restrict__ xv, const u16* __restrict__ wT,
    const float* __restrict__ bq, const float* __restrict__ bk,
    const float* __restrict__ bv, u16* __restrict__ qws, u16* __restrict__ kws,
    u16* __restrict__ vTw) {
  __shared__ __align__(16) char lds[65536];
  const int z = blockIdx.z;
  const u16* A = (z == 0) ? xq : (z == 1) ? xk : xv;
  const u16* Bt = wT + (size_t)z * 262144;
  const float* bias = (z == 0) ? bq : (z == 1) ? bk : bv;
  const int m0 = blockIdx.y * 128, n0 = blockIdx.x * 128;
  f32x4 acc[4][4] = {};
  gemm_core(A, Bt, m0, n0, lds, acc);
  const int lane = threadIdx.x & 63, wave = threadIdx.x >> 6;
  const int wm = wave >> 1, wn = wave & 1;
#pragma unroll
  for (int j = 0; j < 4; ++j) {
    const int n = n0 + wn * 64 + j * 16 + (lane & 15);
    const float bn = bias[n];
    const int h = n >> 6, dh = n & 63;
#pragma unroll
    for (int i = 0; i < 4; ++i) {
#pragma unroll
      for (int r = 0; r < 4; ++r) {
        const int rg = m0 + wm * 64 + i * 16 + ((lane >> 4) << 2) + r;
        const int b = rg >> 11, s = rg & 2047;
        const int bh = b * 8 + h;
        const float val = acc[i][j][r] + bn;
        if (z == 0) {
          qws[((size_t)bh * 2048 + s) * 64 + dh] = f2bf(val * QSCALE);
        } else if (z == 1) {
          kws[((size_t)bh * 2048 + s) * 64 + dh] = f2bf(val);
        } else {
          vTw[((size_t)bh * 64 + dh) * 2048 + s] = f2bf(val);
        }
      }
    }
  }
}

// ---------------- flash attention, split-KV, swapped-QK layout ----------------
// grid (32 qt, 32 bh); 512 threads = 8 waves; waves 0-3 keys [0,1024),
// waves 4-7 keys [1024,2048), same 64 q-rows (16 per wave).
// QK^T computed as mfma(K,Q): lane holds S[key=t*16+hi*4+r][q=lane&15]
// -> P row (q) is lane-local: P-store = 4 x ds_write_b64, denom = 1 scalar.
__global__ __launch_bounds__(512, 4) void attn_fwd(
    const u16* __restrict__ qws, const u16* __restrict__ kws,
    const u16* __restrict__ vTw, const int* __restrict__ mask,
    u16* __restrict__ attn) {
  __shared__ __align__(16) char ldsK[32768];  // [2 halves][2 bufs][64x64 bf16]
  __shared__ __align__(16) char ldsV[32768];  // [2 halves][2 bufs][64dh x 64key bf16]
  __shared__ __align__(16) char plds[16384];  // [8 waves][16 q x 64 key bf16]
  const int qt = blockIdx.x;
  const int bh = blockIdx.y;
  const int b = bh >> 3;
  const int tid = threadIdx.x;
  const int lane = tid & 63, wave = tid >> 6;
  const int half = wave >> 2, wl = wave & 3;
  const int hi = lane >> 4;
  const int q15 = lane & 15;

  // hoisted invariant address pieces
  const int rb = q15 * 128;            // row-byte for q- or key- or dh-rows
  const int xorb = (lane & 7) << 4;    // XOR swizzle term (row&7 == lane&7)
  const int kx0 = ((hi) ^ (lane & 7)) << 4;      // kk=0 column base
  const int kx1 = ((4 + hi) ^ (lane & 7)) << 4;  // kk=1 column base
  const int px0 = (hi * 16) ^ xorb;              // P-read kk=0
  const int px1 = (64 + hi * 16) ^ xorb;         // P-read kk=1

  // Q fragments (already scaled): B-operand, q = lane&15, k = kk*32+hi*8+j
  const u16* qbase = qws + ((size_t)bh * 2048 + qt * 64 + wl * 16) * 64;
  bf16x8 qa[2];
#pragma unroll
  for (int kk = 0; kk < 2; ++kk)
    qa[kk] = *(const bf16x8*)(qbase + q15 * 64 + kk * 32 + hi * 8);

  char* myK = ldsK + half * 16384;
  char* myV = ldsV + half * 16384;
  const int srow = wl * 8 + (lane >> 3);  // 0..31 within half's staging group
  const int sc16 = lane & 7;

  auto stage = [&](int buf, int ktg) {
#pragma unroll
    for (int c = 0; c < 2; ++c) {
      const int row = c * 32 + srow;
      const int xc = (sc16 ^ (row & 7)) << 3;
      gload16(kws + ((size_t)bh * 2048 + ktg * 64 + row) * 64 + xc,
              myK + buf * 8192 + c * 4096 + (wl << 10));
      gload16(vTw + ((size_t)bh * 64 + row) * 2048 + ktg * 64 + xc,
              myV + buf * 8192 + c * 4096 + (wl << 10));
    }
  };

  float rs = 0.f;     // per-lane softmax denom partial (keys are lane-local)
  f32x4 o[4] = {};
  char* pw = plds + wave * 2048;

  stage(0, half * 16);
  __syncthreads();

  for (int kt = 0; kt < 16; ++kt) {
    const int cur = kt & 1;
    const int ktg = half * 16 + kt;

    // mask for this lane's 4 keys per t: key = ktg*64 + t*16 + hi*4 + r
    int4 mm[4];
#pragma unroll
    for (int t = 0; t < 4; ++t)
      mm[t] = *(const int4*)(mask + b * 2048 + ktg * 64 + t * 16 + hi * 4);

    if (kt < 15) stage(cur ^ 1, ktg + 1);

    // ---- S^T = K Q^T : lane holds S[key=t*16+hi*4+r][q=lane&15] ----
    const char* kb = myK + cur * 8192;
    f32x4 sv[4] = {};
    __builtin_amdgcn_s_setprio(1);
#pragma unroll
    for (int t = 0; t < 4; ++t) {
      const bf16x8 kf0 = *(const bf16x8*)(kb + t * 2048 + rb + kx0);
      const bf16x8 kf1 = *(const bf16x8*)(kb + t * 2048 + rb + kx1);
      sv[t] = __builtin_amdgcn_mfma_f32_16x16x32_bf16(kf0, qa[0], sv[t], 0, 0, 0);
      sv[t] = __builtin_amdgcn_mfma_f32_16x16x32_bf16(kf1, qa[1], sv[t], 0, 0, 0);
    }
    __builtin_amdgcn_s_setprio(0);

    // ---- mask + exp2 + denom + P->LDS (4 x b64, swizzled) ----
#pragma unroll
    for (int t = 0; t < 4; ++t) {
      const int mmv[4] = {mm[t].x, mm[t].y, mm[t].z, mm[t].w};
      bf16x4 pk;
#pragma unroll
      for (int r = 0; r < 4; ++r) {
        const float p =
            __builtin_amdgcn_exp2f(sv[t][r] + (mmv[r] ? MASKNEG : 0.0f));
        rs += p;
        pk[r] = (__bf16)p;
      }
      *(bf16x4*)(pw + rb + ((t * 32 + hi * 8) ^ xorb)) = pk;
    }

    // ---- O += P V ----
    const char* vb = myV + cur * 8192;
    __builtin_amdgcn_s_setprio(1);
#pragma unroll
    for (int kk = 0; kk < 2; ++kk) {
      const bf16x8 pa = *(const bf16x8*)(pw + rb + (kk ? px1 : px0));
#pragma unroll
      for (int dt = 0; dt < 4; ++dt) {
        const bf16x8 vf =
            *(const bf16x8*)(vb + dt * 2048 + rb + (kk ? kx1 : kx0));
        o[dt] = __builtin_amdgcn_mfma_f32_16x16x32_bf16(pa, vf, o[dt], 0, 0, 0);
      }
    }
    __builtin_amdgcn_s_setprio(0);
    __syncthreads();
  }

  // ---- denom: reduce across hi-groups (keys) -> l(q=lane&15) ----
  float lred = rs;
  lred += __shfl_xor(lred, 16);
  lred += __shfl_xor(lred, 32);
  // redistribute: o[dt][r] lives at q = hi*4+r -> fetch l for that q
  float lq[4];
#pragma unroll
  for (int r = 0; r < 4; ++r) lq[r] = __shfl(lred, hi * 4 + r);

  // ---- merge halves via LDS (K/V regions are dead now) ----
  float* oSh = (float*)ldsK;  // 4 waves x 16q x 64dh f32 = 16 KB
  float* lSh = (float*)ldsV;  // 4 waves x 16 f32
  if (half == 1) {
#pragma unroll
    for (int dt = 0; dt < 4; ++dt)
#pragma unroll
      for (int r = 0; r < 4; ++r)
        oSh[wl * 1024 + (hi * 4 + r) * 64 + dt * 16 + q15] = o[dt][r];
    if (hi == 0) lSh[wl * 16 + q15] = lred;
  }
  __syncthreads();
  if (half == 0) {
    const int h = bh & 7;
    float invl[4];
#pragma unroll
    for (int r = 0; r < 4; ++r)
      invl[r] = 1.0f / (lq[r] + lSh[wl * 16 + hi * 4 + r]);
    const int sq0 = qt * 64 + wl * 16 + hi * 4;
#pragma unroll
    for (int dt = 0; dt < 4; ++dt) {
      const int dcol = h * 64 + dt * 16 + q15;
#pragma unroll
      for (int r = 0; r < 4; ++r) {
        const float val =
            (o[dt][r] + oSh[wl * 1024 + (hi * 4 + r) * 64 + dt * 16 + q15]) *
            invl[r];
        attn[(size_t)(b * 2048 + sq0 + r) * 512 + dcol] = f2bf(val);
      }
    }
  }
}

// ---------------- output projection -> f32 ----------------
__global__ __launch_bounds__(256) void gemm_out(const u16* __restrict__ attn,
                                                const u16* __restrict__ woT,
                                                const float* __restrict__ bo,
                                                float* __restrict__ out) {
  __shared__ __align__(16) char lds[65536];
  const int m0 = blockIdx.y * 128, n0 = blockIdx.x * 128;
  f32x4 acc[4][4] = {};
  gemm_core(attn, woT, m0, n0, lds, acc);
  const int lane = threadIdx.x & 63, wave = threadIdx.x >> 6;
  const int wm = wave >> 1, wn = wave & 1;
#pragma unroll
  for (int j = 0; j < 4; ++j) {
    const int n = n0 + wn * 64 + j * 16 + (lane & 15);
    const float bn = bo[n];
#pragma unroll
    for (int i = 0; i < 4; ++i) {
      const int rbase = m0 + wm * 64 + i * 16 + ((lane >> 4) << 2);
#pragma unroll
      for (int r = 0; r < 4; ++r)
        out[(size_t)(rbase + r) * 512 + n] = acc[i][j][r] + bn;
    }
  }
}

extern "C" void kernel_launch(void* const* d_in, const int* in_sizes, int n_in,
                              void* d_out, int out_size, void* d_ws,
                              size_t ws_size, hipStream_t stream) {
  (void)in_sizes; (void)n_in; (void)out_size; (void)ws_size;
  const float* q = (const float*)d_in[0];
  const float* k = (const float*)d_in[1];
  const float* v = (const float*)d_in[2];
  const int* mask = (const int*)d_in[3];
  const float* wq = (const float*)d_in[4];
  const float* bq = (const float*)d_in[5];
  const float* wk = (const float*)d_in[6];
  const float* bk = (const float*)d_in[7];
  const float* wv = (const float*)d_in[8];
  const float* bv = (const float*)d_in[9];
  const float* wo = (const float*)d_in[10];
  const float* bo = (const float*)d_in[11];

  u16* xq = (u16*)d_ws;           // [8192][512] bf16 (3 inputs back-to-back)
  u16* xk = xq + 4194304;
  u16* xv = xk + 4194304;
  u16* wT = xv + 4194304;         // 4 x [512][512] bf16 transposed
  u16* qws = wT + 1048576;        // [32 bh][2048][64] bf16, pre-scaled
  u16* kws = qws + 4194304;       // [32 bh][2048][64] bf16
  u16* vTw = kws + 4194304;       // [32 bh][64][2048] bf16 (transposed)
  u16* attn = xq;                 // alias: xq is dead after gemm_qkv
  float* out = (float*)d_out;

  conv_in<<<dim3(2048, 1, 3), 256, 0, stream>>>(q, k, v, xq);
  conv_w<<<dim3(8, 8, 4), 256, 0, stream>>>(wq, wk, wv, wo, wT);
  gemm_qkv<<<dim3(4, 64, 3), 256, 0, stream>>>(xq, xk, xv, wT, bq, bk, bv, qws,
                                               kws, vTw);
  attn_fwd<<<dim3(32, 32), 512, 0, stream>>>(qws, kws, vTw, mask, attn);
  gemm_out<<<dim3(4, 64), 256, 0, stream>>>(attn, wT + 786432, bo, out);
}

// Round 5
// 104.384 us; speedup vs baseline: 1.1800x; 1.1800x over previous
//
#include <hip/hip_runtime.h>
#include <stdint.h>

// B=4, S=2048, D=512, H=8, DH=64
#define QSCALE (0.125f * 1.44269504088896340736f)  // 1/sqrt(DH) * log2(e), folded into Q
#define MASKNEG (-1.442695e9f)                      // -1e9 * log2(e)

typedef unsigned short u16;
typedef unsigned int u32;
typedef __bf16 bf16x8 __attribute__((ext_vector_type(8)));
typedef float f32x4 __attribute__((ext_vector_type(4)));
typedef float f32x16 __attribute__((ext_vector_type(16)));
typedef u16 u16x8 __attribute__((ext_vector_type(8)));
typedef u32 u32x4 __attribute__((ext_vector_type(4)));

__device__ __forceinline__ u16 f2bf(float f) {
  u32 u = __float_as_uint(f);
  u += 0x7fffu + ((u >> 16) & 1u);  // RNE
  return (u16)(u >> 16);
}

__device__ __forceinline__ u32 cvtpk(float lo, float hi) {
  u32 d;
  asm("v_cvt_pk_bf16_f32 %0, %1, %2" : "=v"(d) : "v"(lo), "v"(hi));
  return d;
}

// swap: high 32 lanes of a <-> low 32 lanes of b
__device__ __forceinline__ void plswap(u32& a, u32& b) {
  asm("v_permlane32_swap_b32 %0, %1" : "+v"(a), "+v"(b));
}

__device__ __forceinline__ void gload16(const void* src, void* ldsbase) {
  __builtin_amdgcn_global_load_lds(
      (const __attribute__((address_space(1))) u32*)src,
      (__attribute__((address_space(3))) u32*)ldsbase, 16, 0, 0);
}

// ---------------- input convert: f32 [B,S,D] -> bf16 [8192][512] ----------------
__global__ __launch_bounds__(256) void conv_in(const float* __restrict__ q,
                                               const float* __restrict__ k,
                                               const float* __restrict__ v,
                                               u16* __restrict__ dst) {
  const float* src = (blockIdx.z == 0) ? q : (blockIdx.z == 1) ? k : v;
  u16* d = dst + (size_t)blockIdx.z * 4194304;
  size_t i = ((size_t)blockIdx.x * 256 + threadIdx.x) * 8;
  float4 a = *(const float4*)(src + i);
  float4 b = *(const float4*)(src + i + 4);
  u16x8 ov;
  ov[0] = f2bf(a.x); ov[1] = f2bf(a.y); ov[2] = f2bf(a.z); ov[3] = f2bf(a.w);
  ov[4] = f2bf(b.x); ov[5] = f2bf(b.y); ov[6] = f2bf(b.z); ov[7] = f2bf(b.w);
  *(u16x8*)(d + i) = ov;
}

// ------------- weight convert+transpose: f32 W[k][n] -> bf16 Wt[n][k] -------------
__global__ __launch_bounds__(256) void conv_w(const float* __restrict__ wq,
                                              const float* __restrict__ wk,
                                              const float* __restrict__ wv,
                                              const float* __restrict__ wo,
                                              u16* __restrict__ wT) {
  const float* src = (blockIdx.z == 0) ? wq : (blockIdx.z == 1) ? wk
                    : (blockIdx.z == 2) ? wv : wo;
  u16* dst = wT + (size_t)blockIdx.z * 262144;
  __shared__ float t[64][65];
  const int n0 = blockIdx.x * 64, k0 = blockIdx.y * 64;
  const int lr = threadIdx.x >> 6, lc = threadIdx.x & 63;
#pragma unroll
  for (int it = 0; it < 16; ++it) {
    const int row = it * 4 + lr;  // k offset
    t[row][lc] = src[(size_t)(k0 + row) * 512 + n0 + lc];
  }
  __syncthreads();
#pragma unroll
  for (int it = 0; it < 16; ++it) {
    const int row = it * 4 + lr;  // n offset
    dst[(size_t)(n0 + row) * 512 + k0 + lc] = f2bf(t[lc][row]);
  }
}

// ---------------- shared GEMM core: C[128,128] += A[128,512] * Bt[128,512]^T ----------------
__device__ __forceinline__ void gemm_core(const u16* __restrict__ A,
                                          const u16* __restrict__ Bt,
                                          int m0, int n0, char* lds,
                                          f32x4 acc[4][4]) {
  const int tid = threadIdx.x;
  const int lane = tid & 63;
  const int wave = tid >> 6;
  const int wm = wave >> 1, wn = wave & 1;
  const int srow = tid >> 3;  // 0..31
  const int sc16 = tid & 7;

  auto stage = [&](int buf, int kt) {
    const int k0 = kt * 64;
    char* base = lds + buf * 32768;
#pragma unroll
    for (int c = 0; c < 4; ++c) {
      const int row = c * 32 + srow;
      const int xc = (sc16 ^ (row & 7)) << 3;
      gload16(A + (size_t)(m0 + row) * 512 + k0 + xc,
              base + c * 4096 + (wave << 10));
      gload16(Bt + (size_t)(n0 + row) * 512 + k0 + xc,
              base + 16384 + c * 4096 + (wave << 10));
    }
  };

  auto compute = [&](int buf) {
    const char* bA = lds + buf * 32768;
    const char* bB = bA + 16384;
#pragma unroll
    for (int kk = 0; kk < 2; ++kk) {
      const int c16 = kk * 4 + (lane >> 4);
      bf16x8 av[4], bv[4];
#pragma unroll
      for (int i = 0; i < 4; ++i) {
        const int row = wm * 64 + i * 16 + (lane & 15);
        av[i] = *(const bf16x8*)(bA + row * 128 + ((c16 ^ (row & 7)) << 4));
      }
#pragma unroll
      for (int j = 0; j < 4; ++j) {
        const int row = wn * 64 + j * 16 + (lane & 15);
        bv[j] = *(const bf16x8*)(bB + row * 128 + ((c16 ^ (row & 7)) << 4));
      }
#pragma unroll
      for (int i = 0; i < 4; ++i)
#pragma unroll
        for (int j = 0; j < 4; ++j)
          acc[i][j] = __builtin_amdgcn_mfma_f32_16x16x32_bf16(av[i], bv[j],
                                                              acc[i][j], 0, 0, 0);
    }
  };

  stage(0, 0);
  __syncthreads();
#pragma unroll
  for (int kt = 0; kt < 8; ++kt) {
    const int cur = kt & 1;
    if (kt < 7) stage(cur ^ 1, kt + 1);
    compute(cur);
    __syncthreads();
  }
}

// ---------------- QKV projection (grid.z selects q/k/v) ----------------
__global__ __launch_bounds__(256) void gemm_qkv(
    const u16* __restrict__ xq, const u16* __restrict__ xk,
    const u16* __restrict__ xv, const u16* __restrict__ wT,
    const float* __restrict__ bq, const float* __restrict__ bk,
    const float* __restrict__ bv, u16* __restrict__ qws, u16* __restrict__ kws,
    u16* __restrict__ vTw) {
  __shared__ __align__(16) char lds[65536];
  const int z = blockIdx.z;
  const u16* A = (z == 0) ? xq : (z == 1) ? xk : xv;
  const u16* Bt = wT + (size_t)z * 262144;
  const float* bias = (z == 0) ? bq : (z == 1) ? bk : bv;
  const int m0 = blockIdx.y * 128, n0 = blockIdx.x * 128;
  f32x4 acc[4][4] = {};
  gemm_core(A, Bt, m0, n0, lds, acc);
  const int lane = threadIdx.x & 63, wave = threadIdx.x >> 6;
  const int wm = wave >> 1, wn = wave & 1;
#pragma unroll
  for (int j = 0; j < 4; ++j) {
    const int n = n0 + wn * 64 + j * 16 + (lane & 15);
    const float bn = bias[n];
    const int h = n >> 6, dh = n & 63;
#pragma unroll
    for (int i = 0; i < 4; ++i) {
#pragma unroll
      for (int r = 0; r < 4; ++r) {
        const int rg = m0 + wm * 64 + i * 16 + ((lane >> 4) << 2) + r;
        const int b = rg >> 11, s = rg & 2047;
        const int bh = b * 8 + h;
        const float val = acc[i][j][r] + bn;
        if (z == 0) {
          qws[((size_t)bh * 2048 + s) * 64 + dh] = f2bf(val * QSCALE);
        } else if (z == 1) {
          kws[((size_t)bh * 2048 + s) * 64 + dh] = f2bf(val);
        } else {
          vTw[((size_t)bh * 64 + dh) * 2048 + s] = f2bf(val);
        }
      }
    }
  }
}

// ---------------- flash attention: 32x32 MFMA, in-register P, counted vmcnt ----------------
// grid (32 bh, 16 qt); 512 thr = 8 waves; waves 0-3 keys [0,1024), 4-7 [1024,2048).
// Per wave: 32 q-rows.  QK^T = mfma(K,Q): lane holds S[key=crow(reg,h5)][q=lane&31].
// Mask enters via MFMA acc-init (bias f32 LDS, broadcast reads).  P stays in
// registers: v_cvt_pk_bf16_f32 + v_permlane32_swap_b32 build PV A-frags.
__global__ __launch_bounds__(512, 4) void attn_fwd(
    const u16* __restrict__ qws, const u16* __restrict__ kws,
    const u16* __restrict__ vTw, const int* __restrict__ mask,
    u16* __restrict__ attn) {
  __shared__ __align__(16) char ldsK[32768];   // [2 halves][2 bufs][64 keys][128B]
  __shared__ __align__(16) char ldsV[32768];   // [2 halves][2 bufs][64 dh][128B]
  __shared__ __align__(16) float biasLDS[2048];
  __shared__ float lSh[256];                   // [2 halves][128 rows]

  const int bh = blockIdx.x;
  const int qt = blockIdx.y;
  const int b = bh >> 3;
  const int tid = threadIdx.x;
  const int lane = tid & 63, wave = tid >> 6;
  const int half = wave >> 2, wl = wave & 3;
  const int l31 = lane & 31, h5 = lane >> 5;

  // mask -> additive bias (exp2 domain), once per block
  {
    const int4 m4 = *(const int4*)(mask + b * 2048 + tid * 4);
    float4 bv;
    bv.x = m4.x ? MASKNEG : 0.0f;
    bv.y = m4.y ? MASKNEG : 0.0f;
    bv.z = m4.z ? MASKNEG : 0.0f;
    bv.w = m4.w ? MASKNEG : 0.0f;
    *(float4*)(biasLDS + tid * 4) = bv;
  }
  asm volatile("s_waitcnt lgkmcnt(0)" ::: "memory");

  // Q fragments (already scaled): B-operand, col=q=l31, k = c*16 + h5*8 + j
  const u16* qrow_p = qws + ((size_t)bh * 2048 + qt * 128 + wl * 32 + l31) * 64;
  bf16x8 qb[4];
#pragma unroll
  for (int c = 0; c < 4; ++c)
    qb[c] = *(const bf16x8*)(qrow_p + c * 16 + h5 * 8);

  // hoisted addressing
  const int rowb = l31 * 128;
  int kxs[4];
#pragma unroll
  for (int c = 0; c < 4; ++c) kxs[c] = ((2 * c + h5) ^ (l31 & 7)) << 4;

  char* myK = ldsK + half * 16384;
  char* myV = ldsV + half * 16384;
  const int srow = wl * 8 + (lane >> 3);
  const int sc16 = lane & 7;

  auto stage = [&](int buf, int ktg) {
#pragma unroll
    for (int c = 0; c < 2; ++c) {
      const int row = c * 32 + srow;
      const int xc = (sc16 ^ (row & 7)) << 3;
      gload16(kws + ((size_t)bh * 2048 + ktg * 64 + row) * 64 + xc,
              myK + buf * 8192 + c * 4096 + (wl << 10));
      gload16(vTw + ((size_t)bh * 64 + row) * 2048 + ktg * 64 + xc,
              myV + buf * 8192 + c * 4096 + (wl << 10));
    }
  };

  f32x16 o0 = {}, o1 = {};
  float rsp0 = 0.f, rsp1 = 0.f, rsp2 = 0.f, rsp3 = 0.f;

  auto do_subtile = [&](const char* kb, const char* vb, const float* biasT,
                        int stByte, int c0) {
    // acc init = mask bias (broadcast b128 reads)
    f32x16 sv;
#pragma unroll
    for (int g = 0; g < 4; ++g) {
      const f32x4 bq4 = *(const f32x4*)(biasT + g * 8 + h5 * 4);
      sv[g * 4 + 0] = bq4[0];
      sv[g * 4 + 1] = bq4[1];
      sv[g * 4 + 2] = bq4[2];
      sv[g * 4 + 3] = bq4[3];
    }
    // S^T += K Q^T
    __builtin_amdgcn_s_setprio(1);
#pragma unroll
    for (int c = 0; c < 4; ++c) {
      const bf16x8 kf = *(const bf16x8*)(kb + stByte + rowb + kxs[c]);
      sv = __builtin_amdgcn_mfma_f32_32x32x16_bf16(kf, qb[c], sv, 0, 0, 0);
    }
    __builtin_amdgcn_s_setprio(0);
    // exp2 (masked keys -> exactly 0) + denom partials
    float p[16];
#pragma unroll
    for (int i = 0; i < 16; ++i) p[i] = __builtin_amdgcn_exp2f(sv[i]);
    rsp0 += p[0] + p[4] + p[8] + p[12];
    rsp1 += p[1] + p[5] + p[9] + p[13];
    rsp2 += p[2] + p[6] + p[10] + p[14];
    rsp3 += p[3] + p[7] + p[11] + p[15];
    // pack P -> PV A-frags via cvt_pk + permlane32_swap (no LDS)
    u32 paw[2][4];
#pragma unroll
    for (int lc = 0; lc < 2; ++lc) {
      u32 a1 = cvtpk(p[lc * 8 + 0], p[lc * 8 + 1]);
      u32 b1 = cvtpk(p[lc * 8 + 4], p[lc * 8 + 5]);
      u32 a2 = cvtpk(p[lc * 8 + 2], p[lc * 8 + 3]);
      u32 b2 = cvtpk(p[lc * 8 + 6], p[lc * 8 + 7]);
      plswap(a1, b1);
      plswap(a2, b2);
      paw[lc][0] = a1; paw[lc][1] = a2; paw[lc][2] = b1; paw[lc][3] = b2;
    }
    // O += P V
    __builtin_amdgcn_s_setprio(1);
#pragma unroll
    for (int lc = 0; lc < 2; ++lc) {
      u32x4 w = {paw[lc][0], paw[lc][1], paw[lc][2], paw[lc][3]};
      const bf16x8 pa = __builtin_bit_cast(bf16x8, w);
      const bf16x8 vf0 = *(const bf16x8*)(vb + rowb + kxs[c0 + lc]);
      o0 = __builtin_amdgcn_mfma_f32_32x32x16_bf16(pa, vf0, o0, 0, 0, 0);
      const bf16x8 vf1 = *(const bf16x8*)(vb + 4096 + rowb + kxs[c0 + lc]);
      o1 = __builtin_amdgcn_mfma_f32_32x32x16_bf16(pa, vf1, o1, 0, 0, 0);
    }
    __builtin_amdgcn_s_setprio(0);
  };

  stage(0, half * 16);

  for (int kt = 0; kt < 16; ++kt) {
    const int cur = kt & 1;
    const int ktg = half * 16 + kt;
    if (kt < 15) {
      stage(cur ^ 1, ktg + 1);
      asm volatile("s_waitcnt vmcnt(4)" ::: "memory");  // own prev loads done
    } else {
      asm volatile("s_waitcnt vmcnt(0)" ::: "memory");
    }
    __builtin_amdgcn_sched_barrier(0);
    __builtin_amdgcn_s_barrier();  // all waves' tile-cur data in LDS
    const char* kb = myK + cur * 8192;
    const char* vb = myV + cur * 8192;
    const float* biasT = biasLDS + ktg * 64;
    do_subtile(kb, vb, biasT, 0, 0);
    do_subtile(kb, vb, biasT + 32, 4096, 2);
    __builtin_amdgcn_sched_barrier(0);
    __builtin_amdgcn_s_barrier();  // reads done before next overwrite
  }

  // ---- denominators: lanes l and l+32 hold complementary key sets of q=l31 ----
  float rs = (rsp0 + rsp1) + (rsp2 + rsp3);
  rs += __shfl_xor(rs, 32);

  // ---- O -> LDS (K/V regions dead), then cooperative merge+normalize+store ----
  float* oSh = (float*)(half ? (void*)ldsV : (void*)ldsK);
#pragma unroll
  for (int reg = 0; reg < 16; ++reg) {
    const int q = (reg & 3) + 8 * (reg >> 2) + 4 * h5;
    oSh[wl * 2048 + q * 64 + l31] = o0[reg];
    oSh[wl * 2048 + q * 64 + 32 + l31] = o1[reg];
  }
  if (h5 == 0) lSh[half * 128 + wl * 32 + l31] = rs;
  __syncthreads();

  const int h = bh & 7;
#pragma unroll
  for (int i = 0; i < 2; ++i) {
    const int idx = tid + i * 512;  // 0..1023 -> 128 rows x 8 col-chunks
    const int row = idx >> 3;
    const int c8 = (idx & 7) * 8;
    const float inv = 1.0f / (lSh[row] + lSh[128 + row]);
    const float* A = (const float*)ldsK + row * 64 + c8;
    const float* Bp = (const float*)ldsV + row * 64 + c8;
    u16x8 ovv;
#pragma unroll
    for (int j = 0; j < 8; ++j) ovv[j] = f2bf((A[j] + Bp[j]) * inv);
    const int grow = b * 2048 + qt * 128 + row;
    *(u16x8*)(attn + (size_t)grow * 512 + h * 64 + c8) = ovv;
  }
}

// ---------------- output projection -> f32 ----------------
__global__ __launch_bounds__(256) void gemm_out(const u16* __restrict__ attn,
                                                const u16* __restrict__ woT,
                                                const float* __restrict__ bo,
                                                float* __restrict__ out) {
  __shared__ __align__(16) char lds[65536];
  const int m0 = blockIdx.y * 128, n0 = blockIdx.x * 128;
  f32x4 acc[4][4] = {};
  gemm_core(attn, woT, m0, n0, lds, acc);
  const int lane = threadIdx.x & 63, wave = threadIdx.x >> 6;
  const int wm = wave >> 1, wn = wave & 1;
#pragma unroll
  for (int j = 0; j < 4; ++j) {
    const int n = n0 + wn * 64 + j * 16 + (lane & 15);
    const float bn = bo[n];
#pragma unroll
    for (int i = 0; i < 4; ++i) {
      const int rbase = m0 + wm * 64 + i * 16 + ((lane >> 4) << 2);
#pragma unroll
      for (int r = 0; r < 4; ++r)
        out[(size_t)(rbase + r) * 512 + n] = acc[i][j][r] + bn;
    }
  }
}

extern "C" void kernel_launch(void* const* d_in, const int* in_sizes, int n_in,
                              void* d_out, int out_size, void* d_ws,
                              size_t ws_size, hipStream_t stream) {
  (void)in_sizes; (void)n_in; (void)out_size; (void)ws_size;
  const float* q = (const float*)d_in[0];
  const float* k = (const float*)d_in[1];
  const float* v = (const float*)d_in[2];
  const int* mask = (const int*)d_in[3];
  const float* wq = (const float*)d_in[4];
  const float* bq = (const float*)d_in[5];
  const float* wk = (const float*)d_in[6];
  const float* bk = (const float*)d_in[7];
  const float* wv = (const float*)d_in[8];
  const float* bv = (const float*)d_in[9];
  const float* wo = (const float*)d_in[10];
  const float* bo = (const float*)d_in[11];

  u16* xq = (u16*)d_ws;           // [8192][512] bf16 (3 inputs back-to-back)
  u16* xk = xq + 4194304;
  u16* xv = xk + 4194304;
  u16* wT = xv + 4194304;         // 4 x [512][512] bf16 transposed
  u16* qws = wT + 1048576;        // [32 bh][2048][64] bf16, pre-scaled
  u16* kws = qws + 4194304;       // [32 bh][2048][64] bf16
  u16* vTw = kws + 4194304;       // [32 bh][64][2048] bf16 (transposed)
  u16* attn = xq;                 // alias: xq is dead after gemm_qkv
  float* out = (float*)d_out;

  conv_in<<<dim3(2048, 1, 3), 256, 0, stream>>>(q, k, v, xq);
  conv_w<<<dim3(8, 8, 4), 256, 0, stream>>>(wq, wk, wv, wo, wT);
  gemm_qkv<<<dim3(4, 64, 3), 256, 0, stream>>>(xq, xk, xv, wT, bq, bk, bv, qws,
                                               kws, vTw);
  attn_fwd<<<dim3(32, 16), 512, 0, stream>>>(qws, kws, vTw, mask, attn);
  gemm_out<<<dim3(4, 64), 256, 0, stream>>>(attn, wT + 786432, bo, out);
}